// Round 7
// baseline (598.973 us; speedup 1.0000x reference)
//
#include <hip/hip_runtime.h>
#include <hip/hip_bf16.h>

// Problem constants
#define BB 32
#define TT 1500
#define TP 1536      // T padded to 6*256 for GEMM tiles
#define EE 512
#define HH 4
#define AA 512
#define NN 2048      // H*A
#define CC 10
#define KCONV 201
#define KAUG 576     // 512 enc + 40 conv + 24 zero pad (9 K-tiles of 64)

typedef __attribute__((ext_vector_type(8))) __bf16 bf16x8;
typedef __attribute__((ext_vector_type(4))) float f32x4;

// ---------- helpers ----------
__device__ __forceinline__ unsigned short f2bf(float x) {
    unsigned int u = __float_as_uint(x);
    u = (u + 0x7fffu + ((u >> 16) & 1u)) >> 16;   // RNE, inputs always finite
    return (unsigned short)u;
}
__device__ __forceinline__ float bf2f(unsigned short u) {
    return __uint_as_float(((unsigned int)u) << 16);
}
__device__ __forceinline__ void glds16(const void* g, void* l) {
    __builtin_amdgcn_global_load_lds(
        (const __attribute__((address_space(1))) unsigned int*)g,
        (__attribute__((address_space(3))) unsigned int*)l, 16, 0, 0);
}
// tanh(x) = 1 - 2/(e^{2x}+1); v_exp_f32+v_rcp_f32, ~5 VALU insts.
__device__ __forceinline__ float tanh_fast(float x) {
    float e = __expf(x * 2.0f);
    return fmaf(-2.0f, __builtin_amdgcn_rcpf(e + 1.0f), 1.0f);
}

// Fused prep kernel: block-range dispatch of 5 independent phases.
#define PREP_DEC0   0
#define PREP_CONV0  32
#define PREP_WT0    7712
#define PREP_PAD0   12320
#define PREP_ENC0   19412
#define PREP_TOTAL  43412

__global__ __launch_bounds__(256) void k_prep(
    const float* __restrict__ enc, const int* __restrict__ xl,
    const float* __restrict__ dec_out, const float* __restrict__ aw_step,
    const float* __restrict__ w_enc, const float* __restrict__ b_enc,
    const float* __restrict__ w_dec, const float* __restrict__ w_conv,
    const float* __restrict__ conv_k,
    unsigned short* __restrict__ Whi, unsigned short* __restrict__ Wlo,
    unsigned short* __restrict__ Ahi, unsigned short* __restrict__ Alo,
    float* __restrict__ dec_a) {
    __shared__ float sbuf[456 + KCONV];
    const int bid = blockIdx.x;
    const int tid = threadIdx.x;

    if (bid < PREP_CONV0) {
        // ---- dec: 32 blocks, w_dec read exactly once ----
        // block = (h, a-chunk of 64); thread: a = chunk*64 + (tid&63), 8 b's each.
        const int h = bid >> 3;
        const int a = ((bid & 7) << 6) + (tid & 63);
        const int bg = tid >> 6;                   // 0..3 -> b = bg*8 + q
        float acc[8] = {0.f, 0.f, 0.f, 0.f, 0.f, 0.f, 0.f, 0.f};
        const float* wp = w_dec + (size_t)h * 512 * 512 + a;
#pragma unroll 4
        for (int d = 0; d < 512; ++d) {
            float w = wp[(size_t)d * 512];
#pragma unroll
            for (int q = 0; q < 8; ++q)
                acc[q] += dec_out[(size_t)(bg * 8 + q) * 512 + d] * w;
        }
        const float be = b_enc[h * 512 + a];
#pragma unroll
        for (int q = 0; q < 8; ++q)
            dec_a[(size_t)(bg * 8 + q) * NN + h * 512 + a] = be + acc[q];
    } else if (bid < PREP_WT0) {
        // ---- conv: grouped 1D conv over aw_step -> A cols [512,552) ----
        int r = bid - PREP_CONV0;                  // 7680 = 6*40*32
        const int tch = r % 6;
        const int hc  = (r / 6) % 40;
        const int b   = r / 240;
        const int h   = hc / 10;
        const int t0  = tch * 256;
        float* sAw = sbuf;
        float* sK  = sbuf + 456;
        for (int i = tid; i < 456; i += 256) {
            int ts = t0 - 100 + i;
            sAw[i] = (ts >= 0 && ts < TT) ? aw_step[((size_t)b * TT + ts) * HH + h] : 0.f;
        }
        if (tid < KCONV) sK[tid] = conv_k[(size_t)hc * KCONV + tid];
        __syncthreads();
        int t = t0 + tid;
        if (t < TT) {
            float acc = 0.f;
            for (int k = 0; k < KCONV; ++k) acc += sAw[tid + k] * sK[k];
            size_t o = ((size_t)b * TP + t) * KAUG + 512 + hc;
            unsigned short hi = f2bf(acc);
            Ahi[o] = hi; Alo[o] = f2bf(acc - bf2f(hi));
        }
    } else if (bid < PREP_PAD0) {
        // ---- wt: W planes [N=2048][KAUG], hi/lo ----
        int idx = (bid - PREP_WT0) * 256 + tid;    // 1,179,648
        int n = idx / KAUG, k = idx % KAUG;
        int h = n >> 9, a = n & 511;
        float val = 0.f;
        if (k < 512) {
            val = w_enc[((size_t)h * 512 + k) * 512 + a];
        } else if (k < 552) {
            int j = k - 512; int h2 = j / 10, c = j % 10;
            if (h2 == h) val = w_conv[((size_t)h * 10 + c) * 512 + a];
        }
        unsigned short hi = f2bf(val);
        Whi[idx] = hi;
        Wlo[idx] = f2bf(val - bf2f(hi));
    } else if (bid < PREP_ENC0) {
        // ---- pad: zero rows >=1500 (all cols) + cols [552,576) (rows <1500) ----
        int idx = (bid - PREP_PAD0) * 256 + tid;
        const int tot1 = BB * 36 * KAUG;           // 663552
        const int tot2 = BB * TT * 24;             // 1152000
        size_t o;
        if (idx < tot1) {
            int b = idx / (36 * KAUG); int r2 = idx % (36 * KAUG);
            int t = 1500 + r2 / KAUG;  int k = r2 % KAUG;
            o = ((size_t)b * TP + t) * KAUG + k;
        } else if (idx < tot1 + tot2) {
            int j = idx - tot1;
            int b = j / (TT * 24); int r2 = j % (TT * 24);
            int t = r2 / 24;       int k = 552 + r2 % 24;
            o = ((size_t)b * TP + t) * KAUG + k;
        } else return;
        Ahi[o] = 0; Alo[o] = 0;
    } else {
        // ---- enc: f32 -> A planes cols [0,512); Alo for heavy 256-row tiles ----
        long idx = (long)(bid - PREP_ENC0) * 256 + tid;   // 6,144,000 float4s
        if (idx >= 6144000L) return;
        long f = idx * 4;
        int b = (int)(f / 768000);
        int r2 = (int)(f % 768000);
        int t = r2 >> 9, e = r2 & 511;
        float4 vv = *reinterpret_cast<const float4*>(enc + f);
        ushort4 h4;
        h4.x = f2bf(vv.x); h4.y = f2bf(vv.y); h4.z = f2bf(vv.z); h4.w = f2bf(vv.w);
        size_t o = ((size_t)b * TP + t) * KAUG + e;
        *reinterpret_cast<ushort4*>(Ahi + o) = h4;
        if (((t & ~255) + 256) > xl[b]) {          // 256-row tile containing t is heavy
            ushort4 l4;
            l4.x = f2bf(vv.x - bf2f(h4.x));
            l4.y = f2bf(vv.y - bf2f(h4.y));
            l4.z = f2bf(vv.z - bf2f(h4.z));
            l4.w = f2bf(vv.w - bf2f(h4.w));
            *reinterpret_cast<ushort4*>(Alo + o) = l4;
        }
    }
}

// ---------- 256x256 GEMM: 8-phase schedule + A-resident XCD remap ----------
// Schedule identical to round 6 (verified): 512 thr / 8 waves (2M x 4N), BK=64,
// nkt = 9 (valid) or 27 (heavy: +hi*lo +lo*hi), 2-buffer LDS 128 KB, 8 phases per
// 2 K-tiles, sliding half-tile stages, counted vmcnt(4) at ph4/ph8 (never drains).
//
// NEW (this round): block-ID remap for XCD L2 residency of the A panel.
//   bid = q*64 + ntile*8 + xcd ; group g = q*8 + xcd -> (b, mtile).
// The 8 ntile-blocks of one (b,mtile) group have bids {g%8, +8, ..., +56} within one
// 64-block window -> same XCD (dispatch round-robin), adjacent slots -> the 288 KB
// A-tile is fetched into that XCD's L2 once and served to all 8 blocks, instead of
// every XCD streaming the whole 75 MB A (round-6 FETCH 403 MB, L3-latency stages).
// W (4.5 MB) is now read by all XCDs but is L3-resident - cheap refetch.
// mtile = 5 - g%6 keeps heavy-first ordering.
__global__ __launch_bounds__(512, 2) void k_gemm(
    const unsigned short* __restrict__ Ahi, const unsigned short* __restrict__ Alo,
    const unsigned short* __restrict__ Whi, const unsigned short* __restrict__ Wlo,
    const float* __restrict__ dec_a, const float* __restrict__ vvec,
    const int* __restrict__ xl, float* __restrict__ energy) {
    __shared__ unsigned short lsA[2][16384];   // [buf][256 rows x 64 cols]
    __shared__ unsigned short lsB[2][16384];
    const int bid = blockIdx.x;                // 1536 = 24 q * 8 ntile * 8 xcd
    const int xcd = bid & 7;
    const int ntile = (bid >> 3) & 7;
    const int g = ((bid >> 6) << 3) + xcd;     // group 0..191, XCD-pinned
    const int b = g / 6;
    const int mtile = 5 - (g % 6);             // heavy-first within each b
    const int m0 = mtile * 256, n0 = ntile * 256;
    const int xlen = xl[b];
    const int nkt = (m0 + 256 <= xlen) ? 9 : 27;
    const int nIter = nkt >> 1;                // 4 or 13 (tail K-tile handled after)

    const int tid = threadIdx.x;
    const int lane = tid & 63, wave = tid >> 6;
    const int wm = wave >> 2, wn = wave & 3;

    f32x4 acc[8][4];
#pragma unroll
    for (int i = 0; i < 8; i++)
#pragma unroll
        for (int j = 0; j < 4; j++) acc[i][j] = (f32x4){0.f, 0.f, 0.f, 0.f};

    // ---- staging addressing (linear LDS dest; inverse-swizzled global source) ----
    const int srow = tid >> 3;                 // 0..63
    const int cg8 = ((tid & 7) ^ (srow & 7)) << 3;
    const size_t aRow0 = ((size_t)b * TP + m0 + srow) * KAUG + cg8;
    const size_t bRow0 = ((size_t)n0 + srow) * KAUG + cg8;

    auto stgA = [&](int buf, int half, const unsigned short* Ap, int k0) {
        const unsigned short* s = Ap + aRow0 + (size_t)half * 128 * KAUG + k0;
        unsigned short* d = &lsA[buf][half * 8192 + tid * 8];
        glds16(s, d);
        glds16(s + (size_t)64 * KAUG, d + 4096);
    };
    auto stgB = [&](int buf, int half, const unsigned short* Bp, int k0) {
        const unsigned short* s = Bp + bRow0 + (size_t)half * 128 * KAUG + k0;
        unsigned short* d = &lsB[buf][half * 8192 + tid * 8];
        glds16(s, d);
        glds16(s + (size_t)64 * KAUG, d + 4096);
    };

    // ---- fragment read offsets (swizzled) ----
    const int l15 = lane & 15, lk = lane >> 4, lsw = lane & 7;
    const int aoff = (((wm << 7) + l15) << 6);         // row*64 elems
    const int boff = (((wn << 6) + l15) << 6);
    const int ac0 = ((lk ^ lsw) << 3);                 // ks=0 chunk
    const int ac1 = (((4 | lk) ^ lsw) << 3);           // ks=1 chunk

    bf16x8 aLo[4][2], aHi[4][2], bLo[2][2], bHi[2][2];

#define RDALO(P) { _Pragma("unroll") for (int i = 0; i < 4; ++i) { \
    aLo[i][0] = *(const bf16x8*)&lsA[P][aoff + i * 1024 + ac0]; \
    aLo[i][1] = *(const bf16x8*)&lsA[P][aoff + i * 1024 + ac1]; } }
#define RDAHI(P) { _Pragma("unroll") for (int i = 0; i < 4; ++i) { \
    aHi[i][0] = *(const bf16x8*)&lsA[P][aoff + (i + 4) * 1024 + ac0]; \
    aHi[i][1] = *(const bf16x8*)&lsA[P][aoff + (i + 4) * 1024 + ac1]; } }
#define RDBLO(P) { _Pragma("unroll") for (int j = 0; j < 2; ++j) { \
    bLo[j][0] = *(const bf16x8*)&lsB[P][boff + j * 1024 + ac0]; \
    bLo[j][1] = *(const bf16x8*)&lsB[P][boff + j * 1024 + ac1]; } }
#define RDBHI(P) { _Pragma("unroll") for (int j = 0; j < 2; ++j) { \
    bHi[j][0] = *(const bf16x8*)&lsB[P][boff + (j + 2) * 1024 + ac0]; \
    bHi[j][1] = *(const bf16x8*)&lsB[P][boff + (j + 2) * 1024 + ac1]; } }
#define MFQ(AARR, IOFF, BARR, JOFF) { \
    _Pragma("unroll") for (int i = 0; i < 4; ++i) \
    _Pragma("unroll") for (int j = 0; j < 2; ++j) { \
        acc[(IOFF) + i][(JOFF) + j] = __builtin_amdgcn_mfma_f32_16x16x32_bf16(AARR[i][0], BARR[j][0], acc[(IOFF) + i][(JOFF) + j], 0, 0, 0); \
        acc[(IOFF) + i][(JOFF) + j] = __builtin_amdgcn_mfma_f32_16x16x32_bf16(AARR[i][1], BARR[j][1], acc[(IOFF) + i][(JOFF) + j], 0, 0, 0); } }
#define PH_ENTER() { __builtin_amdgcn_s_barrier(); \
    asm volatile("s_waitcnt lgkmcnt(0)" ::: "memory"); \
    __builtin_amdgcn_sched_barrier(0); __builtin_amdgcn_s_setprio(1); }
#define PH_EXIT()  { __builtin_amdgcn_s_setprio(0); __builtin_amdgcn_s_barrier(); \
    __builtin_amdgcn_sched_barrier(0); }

    // ---- prologue: kt0 (4 halves) + A(kt1) (2 halves); vmcnt(4) leaves A(kt1) in flight
    stgA(0, 0, Ahi, 0); stgA(0, 1, Ahi, 0);
    stgB(0, 0, Whi, 0); stgB(0, 1, Whi, 0);
    stgA(1, 0, Ahi, 64); stgA(1, 1, Ahi, 64);
    __builtin_amdgcn_sched_barrier(0);
    asm volatile("s_waitcnt vmcnt(4)" ::: "memory");
    __builtin_amdgcn_s_barrier();
    __builtin_amdgcn_sched_barrier(0);

    for (int it = 0; it < nIter; ++it) {
        const int kt0 = it << 1;
        const int ktA = kt0 + 1, ktB = kt0 + 2, ktC = kt0 + 3;
        const unsigned short* BpA = (ktA >= 9 && ktA < 18) ? Wlo : Whi;
        const int kA = ((ktA >= 18) ? ktA - 18 : (ktA >= 9) ? ktA - 9 : ktA) * 64;
        const unsigned short* ApB = (ktB >= 18) ? Alo : Ahi;
        const unsigned short* BpB = (ktB >= 9 && ktB < 18) ? Wlo : Whi;
        const int kB = ((ktB >= 18) ? ktB - 18 : (ktB >= 9) ? ktB - 9 : ktB) * 64;
        const unsigned short* ApC = (ktC >= 18) ? Alo : Ahi;
        const int kC = ((ktC >= 18) ? ktC - 18 : (ktC >= 9) ? ktC - 9 : ktC) * 64;
        const bool notLast = (it != nIter - 1);

        // ---- ph1 (kt0, buf0): Mlo x Nlo ----
        RDALO(0); RDBLO(0);
        stgB(1, 0, BpA, kA);
        PH_ENTER(); MFQ(aLo, 0, bLo, 0); PH_EXIT();
        // ---- ph2: Mhi x Nlo ----
        RDAHI(0);
        stgB(1, 1, BpA, kA);
        PH_ENTER(); MFQ(aHi, 4, bLo, 0); PH_EXIT();
        // ---- ph3: Mlo x Nhi ----
        RDBHI(0);
        stgA(0, 0, ApB, kB);
        PH_ENTER(); MFQ(aLo, 0, bHi, 2); PH_EXIT();
        // ---- ph4: Mhi x Nhi ; vmcnt(4) -> kt0+1 fully landed ----
        stgA(0, 1, ApB, kB);
        __builtin_amdgcn_s_barrier();
        __builtin_amdgcn_sched_barrier(0);
        __builtin_amdgcn_s_setprio(1);
        MFQ(aHi, 4, bHi, 2);
        __builtin_amdgcn_s_setprio(0);
        __builtin_amdgcn_sched_barrier(0);
        asm volatile("s_waitcnt vmcnt(4)" ::: "memory");
        __builtin_amdgcn_s_barrier();
        __builtin_amdgcn_sched_barrier(0);

        // ---- ph5 (kt0+1, buf1): Mlo x Nlo ----
        RDALO(1); RDBLO(1);
        stgB(0, 0, BpB, kB);
        PH_ENTER(); MFQ(aLo, 0, bLo, 0); PH_EXIT();
        // ---- ph6: Mhi x Nlo ----
        RDAHI(1);
        stgB(0, 1, BpB, kB);
        PH_ENTER(); MFQ(aHi, 4, bLo, 0); PH_EXIT();
        // ---- ph7: Mlo x Nhi ----
        RDBHI(1);
        if (notLast) stgA(1, 0, ApC, kC);
        PH_ENTER(); MFQ(aLo, 0, bHi, 2); PH_EXIT();
        // ---- ph8: Mhi x Nhi ; vmcnt(4) -> kt0+2 landed (skip on last iter) ----
        if (notLast) stgA(1, 1, ApC, kC);
        __builtin_amdgcn_s_barrier();
        __builtin_amdgcn_sched_barrier(0);
        __builtin_amdgcn_s_setprio(1);
        MFQ(aHi, 4, bHi, 2);
        __builtin_amdgcn_s_setprio(0);
        __builtin_amdgcn_sched_barrier(0);
        if (notLast) asm volatile("s_waitcnt vmcnt(4)" ::: "memory");
        __builtin_amdgcn_s_barrier();
        __builtin_amdgcn_sched_barrier(0);
    }

    // ---- tail K-tile (nkt odd; buf0): drain once, 4 quadrant phases, no stages ----
    asm volatile("s_waitcnt vmcnt(0)" ::: "memory");
    __builtin_amdgcn_s_barrier();
    __builtin_amdgcn_sched_barrier(0);
    RDALO(0); RDBLO(0);
    asm volatile("s_waitcnt lgkmcnt(0)" ::: "memory");
    __builtin_amdgcn_sched_barrier(0);
    MFQ(aLo, 0, bLo, 0);
    RDAHI(0);
    asm volatile("s_waitcnt lgkmcnt(0)" ::: "memory");
    __builtin_amdgcn_sched_barrier(0);
    MFQ(aHi, 4, bLo, 0);
    RDBHI(0);
    asm volatile("s_waitcnt lgkmcnt(0)" ::: "memory");
    __builtin_amdgcn_sched_barrier(0);
    MFQ(aLo, 0, bHi, 2);
    MFQ(aHi, 4, bHi, 2);
#undef RDALO
#undef RDAHI
#undef RDBLO
#undef RDBHI
#undef MFQ
#undef PH_ENTER
#undef PH_EXIT

    // Epilogue: x = acc + dec_a[b][n]; energy += tanh(x)*v[n], reduced over A-dim
    const int h = ntile >> 1;            // 256-wide tile lies inside one head (512)
    const int kg = lane >> 4;
    float dv[4], vv[4];
#pragma unroll
    for (int j = 0; j < 4; j++) {
        int ng = n0 + wn * 64 + j * 16 + (lane & 15);
        dv[j] = dec_a[(size_t)b * NN + ng];
        vv[j] = vvec[ng];
    }
#pragma unroll
    for (int i = 0; i < 8; i++) {
        float part[4] = {0.f, 0.f, 0.f, 0.f};
#pragma unroll
        for (int j = 0; j < 4; j++)
#pragma unroll
            for (int rr = 0; rr < 4; rr++)
                part[rr] += tanh_fast(acc[i][j][rr] + dv[j]) * vv[j];
#pragma unroll
        for (int rr = 0; rr < 4; rr++) {
            float s = part[rr];
            s += __shfl_xor(s, 1, 64);
            s += __shfl_xor(s, 2, 64);
            s += __shfl_xor(s, 4, 64);
            s += __shfl_xor(s, 8, 64);
            if ((lane & 15) == 0) {
                int t = m0 + wm * 128 + i * 16 + kg * 4 + rr;
                if (t < TT)
                    atomicAdd(&energy[((size_t)b * HH + h) * TP + t], s);
            }
        }
    }
}

// ---------- masked softmax over time (replicates energy * (+1 / -1024) mask) ----------
__global__ __launch_bounds__(512) void k_softmax(const float* __restrict__ energy,
                                                 const int* __restrict__ x_lens,
                                                 float* __restrict__ aw) {
    const int b = blockIdx.x >> 2, h = blockIdx.x & 3;
    const int tid = threadIdx.x;
    __shared__ float sE[TT];
    __shared__ float red[512];
    const int xlen = x_lens[b];
    float lmax = -3.4e38f;
    for (int t = tid; t < TT; t += 512) {
        float e = energy[((size_t)b * HH + h) * TP + t];
        float m = (t < xlen) ? e : e * -1024.0f;
        sE[t] = m;
        lmax = fmaxf(lmax, m);
    }
    red[tid] = lmax; __syncthreads();
    for (int s = 256; s > 0; s >>= 1) { if (tid < s) red[tid] = fmaxf(red[tid], red[tid + s]); __syncthreads(); }
    float mx = red[0]; __syncthreads();
    float lsum = 0.f;
    for (int t = tid; t < TT; t += 512) {
        float ex = expf(sE[t] - mx);
        sE[t] = ex; lsum += ex;
    }
    red[tid] = lsum; __syncthreads();
    for (int s = 256; s > 0; s >>= 1) { if (tid < s) red[tid] += red[tid + s]; __syncthreads(); }
    float sum = red[0];
    for (int t = tid; t < TT; t += 512)
        aw[((size_t)b * TT + t) * HH + h] = sE[t] / sum;
}

// ---------- ctx_h[b][h][e] = sum_t aw[b][t][h] * enc[b][t][e] ----------
__global__ __launch_bounds__(512) void k_ctx(const float* __restrict__ enc,
                                             const float* __restrict__ aw,
                                             float* __restrict__ ctx_h) {
    const int chunk = blockIdx.x, b = blockIdx.y;
    const int t0 = chunk * 64;
    const int nt = (TT - t0 < 64) ? (TT - t0) : 64;
    __shared__ float sA[64 * 4];
    const int tid = threadIdx.x;
    for (int i = tid; i < nt * 4; i += 512)
        sA[i] = aw[((size_t)b * TT + t0) * HH + i];
    __syncthreads();
    float a0 = 0.f, a1 = 0.f, a2 = 0.f, a3 = 0.f;
    const float* ep = enc + ((size_t)b * TT + t0) * EE + tid;
    if (nt == 64) {
#pragma unroll 8
        for (int tt = 0; tt < 64; ++tt) {
            float ev = ep[(size_t)tt * EE];
            a0 += sA[tt * 4 + 0] * ev; a1 += sA[tt * 4 + 1] * ev;
            a2 += sA[tt * 4 + 2] * ev; a3 += sA[tt * 4 + 3] * ev;
        }
    } else {
        for (int tt = 0; tt < nt; ++tt) {
            float ev = ep[(size_t)tt * EE];
            a0 += sA[tt * 4 + 0] * ev; a1 += sA[tt * 4 + 1] * ev;
            a2 += sA[tt * 4 + 2] * ev; a3 += sA[tt * 4 + 3] * ev;
        }
    }
    atomicAdd(&ctx_h[((size_t)b * HH + 0) * EE + tid], a0);
    atomicAdd(&ctx_h[((size_t)b * HH + 1) * EE + tid], a1);
    atomicAdd(&ctx_h[((size_t)b * HH + 2) * EE + tid], a2);
    atomicAdd(&ctx_h[((size_t)b * HH + 3) * EE + tid], a3);
}

// ---------- ctx = ctx_h @ w_mha + b_mha ----------
__global__ __launch_bounds__(256) void k_mha(const float* __restrict__ ctx_h,
                                             const float* __restrict__ w_mha,
                                             const float* __restrict__ b_mha,
                                             float* __restrict__ out) {
    __shared__ float sred[256];
    const int tid = threadIdx.x;
    const int b  = blockIdx.x >> 2;
    const int eo = ((blockIdx.x & 3) << 7) + (tid & 127);
    const int kg = tid >> 7;                   // 0..1, 1024 k each
    const float* c = ctx_h + (size_t)b * NN + kg * 1024;
    const float* w = w_mha + ((size_t)kg * 1024) * EE + eo;
    float acc = 0.f;
#pragma unroll 8
    for (int k = 0; k < 1024; ++k) acc += c[k] * w[(size_t)k * EE];
    sred[tid] = acc;
    __syncthreads();
    if (tid < 128)
        out[(size_t)b * EE + eo] = b_mha[eo] + sred[tid] + sred[tid + 128];
}

extern "C" void kernel_launch(void* const* d_in, const int* in_sizes, int n_in,
                              void* d_out, int out_size, void* d_ws, size_t ws_size,
                              hipStream_t stream) {
    (void)in_sizes; (void)n_in; (void)out_size;
    const float* enc    = (const float*)d_in[0];
    const int*   xlen   = (const int*)d_in[1];
    const float* dec    = (const float*)d_in[2];
    const float* aw_in  = (const float*)d_in[3];
    const float* w_enc  = (const float*)d_in[4];
    const float* b_enc  = (const float*)d_in[5];
    const float* w_dec  = (const float*)d_in[6];
    const float* w_conv = (const float*)d_in[7];
    const float* convk  = (const float*)d_in[8];
    const float* v      = (const float*)d_in[9];
    const float* w_mha  = (const float*)d_in[10];
    const float* b_mha  = (const float*)d_in[11];
    float* out = (float*)d_out;

    // ws layout (needs ~119.3 MB)
    char* ws = (char*)d_ws;
    unsigned short* Whi = (unsigned short*)ws;                          // 2,359,296 B
    unsigned short* Wlo = Whi + (size_t)NN * KAUG;                      // 2,359,296 B
    unsigned short* Ahi = (unsigned short*)(ws + 4718592);              // 56,623,104 B
    unsigned short* Alo = Ahi + (size_t)BB * TP * KAUG;                 // 56,623,104 B
    float* dec_a  = (float*)(ws + 117964800);                           //   262,144 B
    float* energy = (float*)(ws + 118226944);                           //   786,432 B
    float* ctx_h  = (float*)(ws + 119013376);                           //   262,144 B
    (void)ws_size;

    hipMemsetAsync(energy, 0, 786432 + 262144, stream);  // energy + ctx_h (contiguous)

    k_prep<<<dim3(PREP_TOTAL), 256, 0, stream>>>(enc, xlen, dec, aw_in, w_enc, b_enc,
                                                 w_dec, w_conv, convk,
                                                 Whi, Wlo, Ahi, Alo, dec_a);
    k_gemm<<<dim3(1536), 512, 0, stream>>>(Ahi, Alo, Whi, Wlo, dec_a, v, xlen, energy);
    k_softmax<<<dim3(BB * HH), 512, 0, stream>>>(energy, xlen, out + 16384);
    k_ctx <<<dim3(24, BB), 512, 0, stream>>>(enc, out + 16384, ctx_h);
    k_mha <<<dim3(128), 256, 0, stream>>>(ctx_h, w_mha, b_mha, out);
}

// Round 8
// 580.633 us; speedup vs baseline: 1.0316x; 1.0316x over previous
//
#include <hip/hip_runtime.h>
#include <hip/hip_bf16.h>

// Problem constants
#define BB 32
#define TT 1500
#define TP 1536      // T padded to 6*256 for GEMM tiles
#define EE 512
#define HH 4
#define AA 512
#define NN 2048      // H*A
#define CC 10
#define KCONV 201
#define KAUG 576     // 512 enc + 40 conv + 24 zero pad (9 K-tiles of 64)

typedef __attribute__((ext_vector_type(8))) __bf16 bf16x8;
typedef __attribute__((ext_vector_type(4))) float f32x4;

// ---------- helpers ----------
__device__ __forceinline__ unsigned short f2bf(float x) {
    unsigned int u = __float_as_uint(x);
    u = (u + 0x7fffu + ((u >> 16) & 1u)) >> 16;   // RNE, inputs always finite
    return (unsigned short)u;
}
__device__ __forceinline__ float bf2f(unsigned short u) {
    return __uint_as_float(((unsigned int)u) << 16);
}
__device__ __forceinline__ void glds16(const void* g, void* l) {
    __builtin_amdgcn_global_load_lds(
        (const __attribute__((address_space(1))) unsigned int*)g,
        (__attribute__((address_space(3))) unsigned int*)l, 16, 0, 0);
}
// tanh(x) = 1 - 2/(e^{2x}+1); v_exp_f32+v_rcp_f32, ~5 VALU insts.
__device__ __forceinline__ float tanh_fast(float x) {
    float e = __expf(x * 2.0f);
    return fmaf(-2.0f, __builtin_amdgcn_rcpf(e + 1.0f), 1.0f);
}

// Fused prep kernel: block-range dispatch of 5 independent phases.
// Pad phase slimmed: only cols [552,576) of rows t<1500 need zeros (garbage there
// would be NaN x W=0 = NaN, poisoning valid rows' dot products). Rows >= 1500 are
// never zeroed: their garbage stays row-local in MFMA and the epilogue discards
// t >= TT before the atomic.
#define PREP_DEC0   0
#define PREP_CONV0  32
#define PREP_WT0    7712
#define PREP_PADC0  12320
#define PREP_ENC0   13445
#define PREP_TOTAL  37445

__global__ __launch_bounds__(256) void k_prep(
    const float* __restrict__ enc, const int* __restrict__ xl,
    const float* __restrict__ dec_out, const float* __restrict__ aw_step,
    const float* __restrict__ w_enc, const float* __restrict__ b_enc,
    const float* __restrict__ w_dec, const float* __restrict__ w_conv,
    const float* __restrict__ conv_k,
    unsigned short* __restrict__ Whi, unsigned short* __restrict__ Wlo,
    unsigned short* __restrict__ Ahi, unsigned short* __restrict__ Alo,
    float* __restrict__ dec_a) {
    __shared__ float sbuf[456 + KCONV];
    const int bid = blockIdx.x;
    const int tid = threadIdx.x;

    if (bid < PREP_CONV0) {
        // ---- dec: 32 blocks, w_dec read exactly once ----
        const int h = bid >> 3;
        const int a = ((bid & 7) << 6) + (tid & 63);
        const int bg = tid >> 6;                   // 0..3 -> b = bg*8 + q
        float acc[8] = {0.f, 0.f, 0.f, 0.f, 0.f, 0.f, 0.f, 0.f};
        const float* wp = w_dec + (size_t)h * 512 * 512 + a;
#pragma unroll 4
        for (int d = 0; d < 512; ++d) {
            float w = wp[(size_t)d * 512];
#pragma unroll
            for (int q = 0; q < 8; ++q)
                acc[q] += dec_out[(size_t)(bg * 8 + q) * 512 + d] * w;
        }
        const float be = b_enc[h * 512 + a];
#pragma unroll
        for (int q = 0; q < 8; ++q)
            dec_a[(size_t)(bg * 8 + q) * NN + h * 512 + a] = be + acc[q];
    } else if (bid < PREP_WT0) {
        // ---- conv: grouped 1D conv over aw_step -> A cols [512,552) ----
        int r = bid - PREP_CONV0;                  // 7680 = 6*40*32
        const int tch = r % 6;
        const int hc  = (r / 6) % 40;
        const int b   = r / 240;
        const int h   = hc / 10;
        const int t0  = tch * 256;
        float* sAw = sbuf;
        float* sK  = sbuf + 456;
        for (int i = tid; i < 456; i += 256) {
            int ts = t0 - 100 + i;
            sAw[i] = (ts >= 0 && ts < TT) ? aw_step[((size_t)b * TT + ts) * HH + h] : 0.f;
        }
        if (tid < KCONV) sK[tid] = conv_k[(size_t)hc * KCONV + tid];
        __syncthreads();
        int t = t0 + tid;
        if (t < TT) {
            float acc = 0.f;
            for (int k = 0; k < KCONV; ++k) acc += sAw[tid + k] * sK[k];
            size_t o = ((size_t)b * TP + t) * KAUG + 512 + hc;
            unsigned short hi = f2bf(acc);
            Ahi[o] = hi; Alo[o] = f2bf(acc - bf2f(hi));
        }
    } else if (bid < PREP_PADC0) {
        // ---- wt: W planes [N=2048][KAUG], hi/lo (zeros for k>=552) ----
        int idx = (bid - PREP_WT0) * 256 + tid;    // 1,179,648
        int n = idx / KAUG, k = idx % KAUG;
        int h = n >> 9, a = n & 511;
        float val = 0.f;
        if (k < 512) {
            val = w_enc[((size_t)h * 512 + k) * 512 + a];
        } else if (k < 552) {
            int j = k - 512; int h2 = j / 10, c = j % 10;
            if (h2 == h) val = w_conv[((size_t)h * 10 + c) * 512 + a];
        }
        unsigned short hi = f2bf(val);
        Whi[idx] = hi;
        Wlo[idx] = f2bf(val - bf2f(hi));
    } else if (bid < PREP_ENC0) {
        // ---- padc: zero A cols [552,576), rows t<1500, both planes, ushort4 ----
        int idx = (bid - PREP_PADC0) * 256 + tid;  // 288,000 = 32*1500*6
        if (idx >= BB * TT * 6) return;
        int u = idx % 6;
        int row = idx / 6;
        int b = row / TT, t = row % TT;
        size_t o = ((size_t)b * TP + t) * KAUG + 552 + u * 4;
        ushort4 z = {0, 0, 0, 0};
        *reinterpret_cast<ushort4*>(Ahi + o) = z;
        *reinterpret_cast<ushort4*>(Alo + o) = z;
    } else {
        // ---- enc: f32 -> A planes cols [0,512); Alo for heavy 256-row tiles ----
        long idx = (long)(bid - PREP_ENC0) * 256 + tid;   // 6,144,000 float4s
        if (idx >= 6144000L) return;
        long f = idx * 4;
        int b = (int)(f / 768000);
        int r2 = (int)(f % 768000);
        int t = r2 >> 9, e = r2 & 511;
        float4 vv = *reinterpret_cast<const float4*>(enc + f);
        ushort4 h4;
        h4.x = f2bf(vv.x); h4.y = f2bf(vv.y); h4.z = f2bf(vv.z); h4.w = f2bf(vv.w);
        size_t o = ((size_t)b * TP + t) * KAUG + e;
        *reinterpret_cast<ushort4*>(Ahi + o) = h4;
        if (((t & ~255) + 256) > xl[b]) {          // 256-row tile containing t is heavy
            ushort4 l4;
            l4.x = f2bf(vv.x - bf2f(h4.x));
            l4.y = f2bf(vv.y - bf2f(h4.y));
            l4.z = f2bf(vv.z - bf2f(h4.z));
            l4.w = f2bf(vv.w - bf2f(h4.w));
            *reinterpret_cast<ushort4*>(Alo + o) = l4;
        }
    }
}

// ---------- 256x256 GEMM: 8-phase schedule, RELAXED waits, R6 balanced map ----------
// Map reverted to round 6 (deterministic perfect XCD balance: consecutive bids
// round-robin across XCDs, so every XCD processes 1/8 of every (b,mtile) group;
// round 7's pinned map had a 13% mtile-parity imbalance and per-kt cost was shown
// identical, so pinning has no upside here).
// Schedule: same barrier/setprio/counted-vmcnt skeleton as round 6, but WITHOUT the
// per-phase explicit lgkmcnt(0)+sched_barrier(0) pins: the ds_reads are plain C++
// loads, so the compiler inserts fine-grained per-use lgkmcnt waits (m97 evidence);
// hand-pinning them serializes each phase on its slowest read (m141 pathology).
// sched_barrier(0) remains ONLY around the ph4/ph8 vmcnt seals: before (stages must
// not sink below their count point) and after (next-kt ds_reads must not hoist above
// the seal). Intra-kt read hoisting across phase barriers is safe (same sealed buf).
__global__ __launch_bounds__(512, 2) void k_gemm(
    const unsigned short* __restrict__ Ahi, const unsigned short* __restrict__ Alo,
    const unsigned short* __restrict__ Whi, const unsigned short* __restrict__ Wlo,
    const float* __restrict__ dec_a, const float* __restrict__ vvec,
    const int* __restrict__ xl, float* __restrict__ energy) {
    __shared__ unsigned short lsA[2][16384];   // [buf][256 rows x 64 cols]
    __shared__ unsigned short lsB[2][16384];
    const int bid = blockIdx.x;                // 1536 = 8 ntile * 6 mtile * 32 b
    const int ntile = bid & 7;
    const int rest = bid >> 3;
    const int b = rest & 31;
    const int mtile = 5 - (rest >> 5);         // heavy-first
    const int m0 = mtile * 256, n0 = ntile * 256;
    const int xlen = xl[b];
    const int nkt = (m0 + 256 <= xlen) ? 9 : 27;
    const int nIter = nkt >> 1;                // 4 or 13 (tail K-tile handled after)

    const int tid = threadIdx.x;
    const int lane = tid & 63, wave = tid >> 6;
    const int wm = wave >> 2, wn = wave & 3;

    f32x4 acc[8][4];
#pragma unroll
    for (int i = 0; i < 8; i++)
#pragma unroll
        for (int j = 0; j < 4; j++) acc[i][j] = (f32x4){0.f, 0.f, 0.f, 0.f};

    // ---- staging addressing (linear LDS dest; inverse-swizzled global source) ----
    const int srow = tid >> 3;                 // 0..63
    const int cg8 = ((tid & 7) ^ (srow & 7)) << 3;
    const size_t aRow0 = ((size_t)b * TP + m0 + srow) * KAUG + cg8;
    const size_t bRow0 = ((size_t)n0 + srow) * KAUG + cg8;

    auto stgA = [&](int buf, int half, const unsigned short* Ap, int k0) {
        const unsigned short* s = Ap + aRow0 + (size_t)half * 128 * KAUG + k0;
        unsigned short* d = &lsA[buf][half * 8192 + tid * 8];
        glds16(s, d);
        glds16(s + (size_t)64 * KAUG, d + 4096);
    };
    auto stgB = [&](int buf, int half, const unsigned short* Bp, int k0) {
        const unsigned short* s = Bp + bRow0 + (size_t)half * 128 * KAUG + k0;
        unsigned short* d = &lsB[buf][half * 8192 + tid * 8];
        glds16(s, d);
        glds16(s + (size_t)64 * KAUG, d + 4096);
    };

    // ---- fragment read offsets (swizzled) ----
    const int l15 = lane & 15, lk = lane >> 4, lsw = lane & 7;
    const int aoff = (((wm << 7) + l15) << 6);         // row*64 elems
    const int boff = (((wn << 6) + l15) << 6);
    const int ac0 = ((lk ^ lsw) << 3);                 // ks=0 chunk
    const int ac1 = (((4 | lk) ^ lsw) << 3);           // ks=1 chunk

    bf16x8 aLo[4][2], aHi[4][2], bLo[2][2], bHi[2][2];

#define RDALO(P) { _Pragma("unroll") for (int i = 0; i < 4; ++i) { \
    aLo[i][0] = *(const bf16x8*)&lsA[P][aoff + i * 1024 + ac0]; \
    aLo[i][1] = *(const bf16x8*)&lsA[P][aoff + i * 1024 + ac1]; } }
#define RDAHI(P) { _Pragma("unroll") for (int i = 0; i < 4; ++i) { \
    aHi[i][0] = *(const bf16x8*)&lsA[P][aoff + (i + 4) * 1024 + ac0]; \
    aHi[i][1] = *(const bf16x8*)&lsA[P][aoff + (i + 4) * 1024 + ac1]; } }
#define RDBLO(P) { _Pragma("unroll") for (int j = 0; j < 2; ++j) { \
    bLo[j][0] = *(const bf16x8*)&lsB[P][boff + j * 1024 + ac0]; \
    bLo[j][1] = *(const bf16x8*)&lsB[P][boff + j * 1024 + ac1]; } }
#define RDBHI(P) { _Pragma("unroll") for (int j = 0; j < 2; ++j) { \
    bHi[j][0] = *(const bf16x8*)&lsB[P][boff + (j + 2) * 1024 + ac0]; \
    bHi[j][1] = *(const bf16x8*)&lsB[P][boff + (j + 2) * 1024 + ac1]; } }
#define MFQ(AARR, IOFF, BARR, JOFF) { \
    _Pragma("unroll") for (int i = 0; i < 4; ++i) \
    _Pragma("unroll") for (int j = 0; j < 2; ++j) { \
        acc[(IOFF) + i][(JOFF) + j] = __builtin_amdgcn_mfma_f32_16x16x32_bf16(AARR[i][0], BARR[j][0], acc[(IOFF) + i][(JOFF) + j], 0, 0, 0); \
        acc[(IOFF) + i][(JOFF) + j] = __builtin_amdgcn_mfma_f32_16x16x32_bf16(AARR[i][1], BARR[j][1], acc[(IOFF) + i][(JOFF) + j], 0, 0, 0); } }
#define PH_ENTER() { __builtin_amdgcn_s_barrier(); __builtin_amdgcn_s_setprio(1); }
#define PH_EXIT()  { __builtin_amdgcn_s_setprio(0); __builtin_amdgcn_s_barrier(); }

    // ---- prologue: kt0 (4 halves) + A(kt1) (2 halves); vmcnt(4) leaves A(kt1) in flight
    stgA(0, 0, Ahi, 0); stgA(0, 1, Ahi, 0);
    stgB(0, 0, Whi, 0); stgB(0, 1, Whi, 0);
    stgA(1, 0, Ahi, 64); stgA(1, 1, Ahi, 64);
    __builtin_amdgcn_sched_barrier(0);
    asm volatile("s_waitcnt vmcnt(4)" ::: "memory");
    __builtin_amdgcn_s_barrier();
    __builtin_amdgcn_sched_barrier(0);

    for (int it = 0; it < nIter; ++it) {
        const int kt0 = it << 1;
        const int ktA = kt0 + 1, ktB = kt0 + 2, ktC = kt0 + 3;
        const unsigned short* BpA = (ktA >= 9 && ktA < 18) ? Wlo : Whi;
        const int kA = ((ktA >= 18) ? ktA - 18 : (ktA >= 9) ? ktA - 9 : ktA) * 64;
        const unsigned short* ApB = (ktB >= 18) ? Alo : Ahi;
        const unsigned short* BpB = (ktB >= 9 && ktB < 18) ? Wlo : Whi;
        const int kB = ((ktB >= 18) ? ktB - 18 : (ktB >= 9) ? ktB - 9 : ktB) * 64;
        const unsigned short* ApC = (ktC >= 18) ? Alo : Ahi;
        const int kC = ((ktC >= 18) ? ktC - 18 : (ktC >= 9) ? ktC - 9 : ktC) * 64;
        const bool notLast = (it != nIter - 1);

        // ---- ph1 (kt0, buf0): Mlo x Nlo ----
        RDALO(0); RDBLO(0);
        stgB(1, 0, BpA, kA);
        PH_ENTER(); MFQ(aLo, 0, bLo, 0); PH_EXIT();
        // ---- ph2: Mhi x Nlo ----
        RDAHI(0);
        stgB(1, 1, BpA, kA);
        PH_ENTER(); MFQ(aHi, 4, bLo, 0); PH_EXIT();
        // ---- ph3: Mlo x Nhi ----
        RDBHI(0);
        stgA(0, 0, ApB, kB);
        PH_ENTER(); MFQ(aLo, 0, bHi, 2); PH_EXIT();
        // ---- ph4: Mhi x Nhi ; SEAL: vmcnt(4) -> kt0+1 fully landed ----
        stgA(0, 1, ApB, kB);
        __builtin_amdgcn_s_barrier();
        __builtin_amdgcn_s_setprio(1);
        MFQ(aHi, 4, bHi, 2);
        __builtin_amdgcn_s_setprio(0);
        __builtin_amdgcn_sched_barrier(0);
        asm volatile("s_waitcnt vmcnt(4)" ::: "memory");
        __builtin_amdgcn_s_barrier();
        __builtin_amdgcn_sched_barrier(0);

        // ---- ph5 (kt0+1, buf1): Mlo x Nlo ----
        RDALO(1); RDBLO(1);
        stgB(0, 0, BpB, kB);
        PH_ENTER(); MFQ(aLo, 0, bLo, 0); PH_EXIT();
        // ---- ph6: Mhi x Nlo ----
        RDAHI(1);
        stgB(0, 1, BpB, kB);
        PH_ENTER(); MFQ(aHi, 4, bLo, 0); PH_EXIT();
        // ---- ph7: Mlo x Nhi ----
        RDBHI(1);
        if (notLast) stgA(1, 0, ApC, kC);
        PH_ENTER(); MFQ(aLo, 0, bHi, 2); PH_EXIT();
        // ---- ph8: Mhi x Nhi ; SEAL: vmcnt(4) -> kt0+2 landed (skip on last iter) ----
        if (notLast) stgA(1, 1, ApC, kC);
        __builtin_amdgcn_s_barrier();
        __builtin_amdgcn_s_setprio(1);
        MFQ(aHi, 4, bHi, 2);
        __builtin_amdgcn_s_setprio(0);
        __builtin_amdgcn_sched_barrier(0);
        if (notLast) asm volatile("s_waitcnt vmcnt(4)" ::: "memory");
        __builtin_amdgcn_s_barrier();
        __builtin_amdgcn_sched_barrier(0);
    }

    // ---- tail K-tile (nkt odd; buf0): drain once, 4 quadrant phases, no stages ----
    asm volatile("s_waitcnt vmcnt(0)" ::: "memory");
    __builtin_amdgcn_s_barrier();
    __builtin_amdgcn_sched_barrier(0);
    RDALO(0); RDBLO(0);
    MFQ(aLo, 0, bLo, 0);
    RDAHI(0);
    MFQ(aHi, 4, bLo, 0);
    RDBHI(0);
    MFQ(aLo, 0, bHi, 2);
    MFQ(aHi, 4, bHi, 2);
#undef RDALO
#undef RDAHI
#undef RDBLO
#undef RDBHI
#undef MFQ
#undef PH_ENTER
#undef PH_EXIT

    // Epilogue: x = acc + dec_a[b][n]; energy += tanh(x)*v[n], reduced over A-dim
    const int h = ntile >> 1;            // 256-wide tile lies inside one head (512)
    const int kg = lane >> 4;
    float dv[4], vv[4];
#pragma unroll
    for (int j = 0; j < 4; j++) {
        int ng = n0 + wn * 64 + j * 16 + (lane & 15);
        dv[j] = dec_a[(size_t)b * NN + ng];
        vv[j] = vvec[ng];
    }
#pragma unroll
    for (int i = 0; i < 8; i++) {
        float part[4] = {0.f, 0.f, 0.f, 0.f};
#pragma unroll
        for (int j = 0; j < 4; j++)
#pragma unroll
            for (int rr = 0; rr < 4; rr++)
                part[rr] += tanh_fast(acc[i][j][rr] + dv[j]) * vv[j];
#pragma unroll
        for (int rr = 0; rr < 4; rr++) {
            float s = part[rr];
            s += __shfl_xor(s, 1, 64);
            s += __shfl_xor(s, 2, 64);
            s += __shfl_xor(s, 4, 64);
            s += __shfl_xor(s, 8, 64);
            if ((lane & 15) == 0) {
                int t = m0 + wm * 128 + i * 16 + kg * 4 + rr;
                if (t < TT)
                    atomicAdd(&energy[((size_t)b * HH + h) * TP + t], s);
            }
        }
    }
}

// ---------- masked softmax over time (replicates energy * (+1 / -1024) mask) ----------
__global__ __launch_bounds__(512) void k_softmax(const float* __restrict__ energy,
                                                 const int* __restrict__ x_lens,
                                                 float* __restrict__ aw) {
    const int b = blockIdx.x >> 2, h = blockIdx.x & 3;
    const int tid = threadIdx.x;
    __shared__ float sE[TT];
    __shared__ float red[512];
    const int xlen = x_lens[b];
    float lmax = -3.4e38f;
    for (int t = tid; t < TT; t += 512) {
        float e = energy[((size_t)b * HH + h) * TP + t];
        float m = (t < xlen) ? e : e * -1024.0f;
        sE[t] = m;
        lmax = fmaxf(lmax, m);
    }
    red[tid] = lmax; __syncthreads();
    for (int s = 256; s > 0; s >>= 1) { if (tid < s) red[tid] = fmaxf(red[tid], red[tid + s]); __syncthreads(); }
    float mx = red[0]; __syncthreads();
    float lsum = 0.f;
    for (int t = tid; t < TT; t += 512) {
        float ex = expf(sE[t] - mx);
        sE[t] = ex; lsum += ex;
    }
    red[tid] = lsum; __syncthreads();
    for (int s = 256; s > 0; s >>= 1) { if (tid < s) red[tid] += red[tid + s]; __syncthreads(); }
    float sum = red[0];
    for (int t = tid; t < TT; t += 512)
        aw[((size_t)b * TT + t) * HH + h] = sE[t] / sum;
}

// ---------- ctx_h[b][h][e] = sum_t aw[b][t][h] * enc[b][t][e] ----------
__global__ __launch_bounds__(512) void k_ctx(const float* __restrict__ enc,
                                             const float* __restrict__ aw,
                                             float* __restrict__ ctx_h) {
    const int chunk = blockIdx.x, b = blockIdx.y;
    const int t0 = chunk * 64;
    const int nt = (TT - t0 < 64) ? (TT - t0) : 64;
    __shared__ float sA[64 * 4];
    const int tid = threadIdx.x;
    for (int i = tid; i < nt * 4; i += 512)
        sA[i] = aw[((size_t)b * TT + t0) * HH + i];
    __syncthreads();
    float a0 = 0.f, a1 = 0.f, a2 = 0.f, a3 = 0.f;
    const float* ep = enc + ((size_t)b * TT + t0) * EE + tid;
    if (nt == 64) {
#pragma unroll 8
        for (int tt = 0; tt < 64; ++tt) {
            float ev = ep[(size_t)tt * EE];
            a0 += sA[tt * 4 + 0] * ev; a1 += sA[tt * 4 + 1] * ev;
            a2 += sA[tt * 4 + 2] * ev; a3 += sA[tt * 4 + 3] * ev;
        }
    } else {
        for (int tt = 0; tt < nt; ++tt) {
            float ev = ep[(size_t)tt * EE];
            a0 += sA[tt * 4 + 0] * ev; a1 += sA[tt * 4 + 1] * ev;
            a2 += sA[tt * 4 + 2] * ev; a3 += sA[tt * 4 + 3] * ev;
        }
    }
    atomicAdd(&ctx_h[((size_t)b * HH + 0) * EE + tid], a0);
    atomicAdd(&ctx_h[((size_t)b * HH + 1) * EE + tid], a1);
    atomicAdd(&ctx_h[((size_t)b * HH + 2) * EE + tid], a2);
    atomicAdd(&ctx_h[((size_t)b * HH + 3) * EE + tid], a3);
}

// ---------- ctx = ctx_h @ w_mha + b_mha ----------
__global__ __launch_bounds__(256) void k_mha(const float* __restrict__ ctx_h,
                                             const float* __restrict__ w_mha,
                                             const float* __restrict__ b_mha,
                                             float* __restrict__ out) {
    __shared__ float sred[256];
    const int tid = threadIdx.x;
    const int b  = blockIdx.x >> 2;
    const int eo = ((blockIdx.x & 3) << 7) + (tid & 127);
    const int kg = tid >> 7;                   // 0..1, 1024 k each
    const float* c = ctx_h + (size_t)b * NN + kg * 1024;
    const float* w = w_mha + ((size_t)kg * 1024) * EE + eo;
    float acc = 0.f;
#pragma unroll 8
    for (int k = 0; k < 1024; ++k) acc += c[k] * w[(size_t)k * EE];
    sred[tid] = acc;
    __syncthreads();
    if (tid < 128)
        out[(size_t)b * EE + eo] = b_mha[eo] + sred[tid] + sred[tid + 128];
}

extern "C" void kernel_launch(void* const* d_in, const int* in_sizes, int n_in,
                              void* d_out, int out_size, void* d_ws, size_t ws_size,
                              hipStream_t stream) {
    (void)in_sizes; (void)n_in; (void)out_size;
    const float* enc    = (const float*)d_in[0];
    const int*   xlen   = (const int*)d_in[1];
    const float* dec    = (const float*)d_in[2];
    const float* aw_in  = (const float*)d_in[3];
    const float* w_enc  = (const float*)d_in[4];
    const float* b_enc  = (const float*)d_in[5];
    const float* w_dec  = (const float*)d_in[6];
    const float* w_conv = (const float*)d_in[7];
    const float* convk  = (const float*)d_in[8];
    const float* v      = (const float*)d_in[9];
    const float* w_mha  = (const float*)d_in[10];
    const float* b_mha  = (const float*)d_in[11];
    float* out = (float*)d_out;

    // ws layout (needs ~119.3 MB)
    char* ws = (char*)d_ws;
    unsigned short* Whi = (unsigned short*)ws;                          // 2,359,296 B
    unsigned short* Wlo = Whi + (size_t)NN * KAUG;                      // 2,359,296 B
    unsigned short* Ahi = (unsigned short*)(ws + 4718592);              // 56,623,104 B
    unsigned short* Alo = Ahi + (size_t)BB * TP * KAUG;                 // 56,623,104 B
    float* dec_a  = (float*)(ws + 117964800);                           //   262,144 B
    float* energy = (float*)(ws + 118226944);                           //   786,432 B
    float* ctx_h  = (float*)(ws + 119013376);                           //   262,144 B
    (void)ws_size;

    hipMemsetAsync(energy, 0, 786432 + 262144, stream);  // energy + ctx_h (contiguous)

    k_prep<<<dim3(PREP_TOTAL), 256, 0, stream>>>(enc, xlen, dec, aw_in, w_enc, b_enc,
                                                 w_dec, w_conv, convk,
                                                 Whi, Wlo, Ahi, Alo, dec_a);
    k_gemm<<<dim3(1536), 512, 0, stream>>>(Ahi, Alo, Whi, Wlo, dec_a, v, xlen, energy);
    k_softmax<<<dim3(BB * HH), 512, 0, stream>>>(energy, xlen, out + 16384);
    k_ctx <<<dim3(24, BB), 512, 0, stream>>>(enc, out + 16384, ctx_h);
    k_mha <<<dim3(128), 256, 0, stream>>>(ctx_h, w_mha, b_mha, out);
}